// Round 3
// baseline (103.464 us; speedup 1.0000x reference)
//
#include <hip/hip_runtime.h>
#include <hip/hip_cooperative_groups.h>
#include <math.h>

namespace cg = cooperative_groups;

// Problem constants (reference: x [8,2,224,224] f32, weights [1,4] f32)
#define BATCH 8
#define CIN   2
#define H     224
#define W     224
#define NH    223
#define NW    223
#define PIXB  (H * W)            // 50176 floats per channel per batch
#define NPB   (CIN * H * W)      // 100352 floats per batch
#define PER_B (NH * NW)          // 49729 outputs per (batch, qubit)
#define BPB2  49                 // blocks per batch
#define NBLK  (BATCH * BPB2)     // 392 blocks total
#define GPR   56                 // col-groups of 4 per row (56*4=224 >= 223)
#define SLOTS (NH * GPR)         // 12488 thread-slots per batch
#define PI_F  3.14159265358979323846f

// ws layout (floats): [0..391] block min partials, [512..903] block max
// partials, [1024..1027] cos(w_q), [1028..1031] sin(w_q)

__global__ __launch_bounds__(256) void fused_quanv(
        const float* __restrict__ x, const float* __restrict__ wts,
        float* __restrict__ ws, float* __restrict__ out) {
    cg::grid_group grid = cg::this_grid();
    const int b  = blockIdx.x / BPB2;
    const int cb = blockIdx.x - b * BPB2;

    // ---------- phase 1: per-block min/max partial over this batch's slice
    {
        const float4* xb = (const float4*)(x + (size_t)b * NPB);
        const int base = cb * 512 + threadIdx.x;     // 512 float4 per block
        float4 v0 = xb[base];
        float4 v1 = xb[base + 256];
        float lmin = fminf(fminf(fminf(v0.x, v0.y), fminf(v0.z, v0.w)),
                           fminf(fminf(v1.x, v1.y), fminf(v1.z, v1.w)));
        float lmax = fmaxf(fmaxf(fmaxf(v0.x, v0.y), fmaxf(v0.z, v0.w)),
                           fmaxf(fmaxf(v1.x, v1.y), fmaxf(v1.z, v1.w)));
        #pragma unroll
        for (int off = 32; off > 0; off >>= 1) {
            lmin = fminf(lmin, __shfl_down(lmin, off, 64));
            lmax = fmaxf(lmax, __shfl_down(lmax, off, 64));
        }
        __shared__ float smin[4], smax[4];
        int wid = threadIdx.x >> 6;
        if ((threadIdx.x & 63) == 0) { smin[wid] = lmin; smax[wid] = lmax; }
        __syncthreads();
        if (threadIdx.x == 0) {
            #pragma unroll
            for (int i = 1; i < 4; ++i) {
                lmin = fminf(lmin, smin[i]);
                lmax = fmaxf(lmax, smax[i]);
            }
            ws[blockIdx.x]       = lmin;
            ws[512 + blockIdx.x] = lmax;
        }
        if (blockIdx.x == 0 && threadIdx.x < 4) {
            float sw, cw;
            __sincosf(wts[threadIdx.x], &sw, &cw);
            ws[1024 + threadIdx.x] = cw;
            ws[1028 + threadIdx.x] = sw;
        }
    }

    grid.sync();

    // ---------- phase 2: reduce this batch's 49 partials (first wave)
    __shared__ float sred[2];
    if (threadIdx.x < 64) {
        float mn = INFINITY, mx = -INFINITY;
        if (threadIdx.x < BPB2) {
            mn = ws[b * BPB2 + threadIdx.x];
            mx = ws[512 + b * BPB2 + threadIdx.x];
        }
        #pragma unroll
        for (int off = 32; off > 0; off >>= 1) {
            mn = fminf(mn, __shfl_xor(mn, off, 64));
            mx = fmaxf(mx, __shfl_xor(mx, off, 64));
        }
        if (threadIdx.x == 0) { sred[0] = mn; sred[1] = mx; }
    }
    __syncthreads();
    const float gmin  = sred[0];
    const float scale = PI_F / (sred[1] - gmin + 1e-8f);

    const float cw0 = ws[1024], cw1 = ws[1025], cw2 = ws[1026], cw3 = ws[1027];
    const float sw0 = ws[1028], sw1 = ws[1029], sw2 = ws[1030], sw3 = ws[1031];

    const int g = cb * 256 + threadIdx.x;      // [0, 12544)
    if (g >= SLOTS) return;
    const int i  = g / GPR;                    // output row, [0,223)
    const int jg = g - i * GPR;
    const int j  = jg * 4;                     // first output col of this group
    const bool full = (j + 3 < NW);            // jg<=54: 4 patches; jg=55: 3

    const float* r0 = x + (size_t)b * NPB + (size_t)i * W + j;  // row i, ch0
    // 16B-aligned: NPB,W multiples of 4 and j%4==0
    float4 p00 = *(const float4*)(r0);                 // row i,   ch0
    float4 p01 = *(const float4*)(r0 + PIXB);          // row i,   ch1
    float4 p10 = *(const float4*)(r0 + W);             // row i+1, ch0
    float4 p11 = *(const float4*)(r0 + W + PIXB);      // row i+1, ch1

    // per-pixel-pair trig: pcc = cos(a)*cos(bb), psa = sin(a)
    float pcc[2][5], psa[2][5];
    #define TRIG(pa, pb, PC, PS) do {                         \
        float _a  = ((pa) - gmin) * scale;                    \
        float _bb = ((pb) - gmin) * scale;                    \
        float _s, _c; __sincosf(_a, &_s, &_c);                \
        (PC) = _c * __cosf(_bb); (PS) = _s; } while (0)

    TRIG(p00.x, p01.x, pcc[0][0], psa[0][0]);
    TRIG(p00.y, p01.y, pcc[0][1], psa[0][1]);
    TRIG(p00.z, p01.z, pcc[0][2], psa[0][2]);
    TRIG(p00.w, p01.w, pcc[0][3], psa[0][3]);
    TRIG(p10.x, p11.x, pcc[1][0], psa[1][0]);
    TRIG(p10.y, p11.y, pcc[1][1], psa[1][1]);
    TRIG(p10.z, p11.z, pcc[1][2], psa[1][2]);
    TRIG(p10.w, p11.w, pcc[1][3], psa[1][3]);
    if (full) {
        float e0 = r0[4], e1 = (r0 + PIXB)[4];
        float e2 = (r0 + W)[4], e3 = (r0 + W + PIXB)[4];
        TRIG(e0, e1, pcc[0][4], psa[0][4]);
        TRIG(e2, e3, pcc[1][4], psa[1][4]);
    } else {
        pcc[0][4] = psa[0][4] = pcc[1][4] = psa[1][4] = 0.0f;
    }

    const int np = full ? 4 : 3;
    const size_t obase = ((size_t)(b * 4) * NH + i) * NW + j;  // q-plane stride PER_B
    #pragma unroll
    for (int dj = 0; dj < 4; ++dj) {
        if (dj >= np) break;
        float z0 = pcc[0][dj]     * cw0 - psa[0][dj]     * sw0;
        float z1 = pcc[0][dj + 1] * cw1 - psa[0][dj + 1] * sw1;
        float z2 = pcc[1][dj]     * cw2 - psa[1][dj]     * sw2;
        float z3 = pcc[1][dj + 1] * cw3 - psa[1][dj + 1] * sw3;
        float z01 = z0 * z1;
        out[obase + dj]             = z1 * z2 * z3;
        out[obase + dj + PER_B]     = z01;
        out[obase + dj + 2 * PER_B] = z01 * z2;
        out[obase + dj + 3 * PER_B] = z01 * z2 * z3;
    }
}

extern "C" void kernel_launch(void* const* d_in, const int* in_sizes, int n_in,
                              void* d_out, int out_size, void* d_ws, size_t ws_size,
                              hipStream_t stream) {
    const float* x   = (const float*)d_in[0];   // [8,2,224,224] f32
    const float* wts = (const float*)d_in[1];   // [1,4] f32
    float* out = (float*)d_out;                 // [8,4,223,223] f32
    float* ws  = (float*)d_ws;

    void* args[] = { (void*)&x, (void*)&wts, (void*)&ws, (void*)&out };
    hipLaunchCooperativeKernel((void*)fused_quanv, dim3(NBLK), dim3(256),
                               args, 0, stream);
}

// Round 4
// 61.665 us; speedup vs baseline: 1.6778x; 1.6778x over previous
//
#include <hip/hip_runtime.h>
#include <math.h>

// Problem constants (reference: x [8,2,224,224] f32, weights [1,4] f32)
#define BATCH 8
#define CIN   2
#define H     224
#define W     224
#define NH    223
#define NW    223
#define PIXB  (H * W)            // 50176 floats per channel per batch
#define NPB   (CIN * H * W)      // 100352 floats per batch
#define PER_B (NH * NW)          // 49729 outputs per (batch, qubit)
#define BPB   32                 // reduction blocks per batch
#define BPB2  49                 // compute blocks per batch
#define GPR   56                 // col-groups of 4 per row (56*4=224 >= 223)
#define SLOTS (NH * GPR)         // 12488 thread-slots per batch
#define PI_F  3.14159265358979323846f

// ws layout (floats): [0..255] block min partials (b*32+cb),
// [256..511] block max partials, [1024..1027] cos(w_q), [1028..1031] sin(w_q)

// Kernel 1: per-block partial min/max, no atomics, no init. Block 0 also
// writes the weight cos/sin table.
__global__ __launch_bounds__(256) void minmax_kernel(
        const float* __restrict__ x, const float* __restrict__ wts,
        float* __restrict__ ws) {
    int b  = blockIdx.x / BPB;
    int cb = blockIdx.x - b * BPB;
    const float4* xb = (const float4*)(x + (size_t)b * NPB);
    const int per = (NPB / 4) / BPB;    // 784 float4 per block
    float lmin =  INFINITY, lmax = -INFINITY;
    for (int idx = cb * per + threadIdx.x; idx < (cb + 1) * per; idx += 256) {
        float4 v = xb[idx];
        lmin = fminf(lmin, fminf(fminf(v.x, v.y), fminf(v.z, v.w)));
        lmax = fmaxf(lmax, fmaxf(fmaxf(v.x, v.y), fmaxf(v.z, v.w)));
    }
    #pragma unroll
    for (int off = 32; off > 0; off >>= 1) {
        lmin = fminf(lmin, __shfl_down(lmin, off, 64));
        lmax = fmaxf(lmax, __shfl_down(lmax, off, 64));
    }
    __shared__ float smin[4], smax[4];
    int wid = threadIdx.x >> 6;
    if ((threadIdx.x & 63) == 0) { smin[wid] = lmin; smax[wid] = lmax; }
    __syncthreads();
    if (threadIdx.x == 0) {
        #pragma unroll
        for (int i = 1; i < 4; ++i) {
            lmin = fminf(lmin, smin[i]);
            lmax = fmaxf(lmax, smax[i]);
        }
        ws[blockIdx.x]       = lmin;
        ws[256 + blockIdx.x] = lmax;
    }
    if (blockIdx.x == 0 && threadIdx.x < 4) {
        float sw, cw;
        __sincosf(wts[threadIdx.x], &sw, &cw);
        ws[1024 + threadIdx.x] = cw;
        ws[1028 + threadIdx.x] = sw;
    }
}

// Kernel 2: analytic circuit, 4 outputs per thread, float4 loads.
// z_q = cos(a_q)cos(b_q)cos(w_q) - sin(a_q)sin(w_q)
// out[b,0]=z1z2z3  out[b,1]=z0z1  out[b,2]=z0z1z2  out[b,3]=z0z1z2z3
// Grid: (BPB2, BATCH).
__global__ __launch_bounds__(256) void quanv_kernel(
        const float* __restrict__ x, const float* __restrict__ ws,
        float* __restrict__ out) {
    const int b = blockIdx.y;

    // reduce this batch's 32 partials in the first 32 lanes, broadcast via LDS
    __shared__ float sred[2];
    if (threadIdx.x < 32) {
        float mn = ws[b * BPB + threadIdx.x];
        float mx = ws[256 + b * BPB + threadIdx.x];
        #pragma unroll
        for (int off = 16; off > 0; off >>= 1) {
            mn = fminf(mn, __shfl_xor(mn, off, 32));
            mx = fmaxf(mx, __shfl_xor(mx, off, 32));
        }
        if (threadIdx.x == 0) { sred[0] = mn; sred[1] = mx; }
    }
    __syncthreads();
    const float gmin  = sred[0];
    const float scale = PI_F / (sred[1] - gmin + 1e-8f);

    const float cw0 = ws[1024], cw1 = ws[1025], cw2 = ws[1026], cw3 = ws[1027];
    const float sw0 = ws[1028], sw1 = ws[1029], sw2 = ws[1030], sw3 = ws[1031];

    const int g = blockIdx.x * 256 + threadIdx.x;   // [0, 12544)
    if (g >= SLOTS) return;
    const int i  = g / GPR;                  // output row, [0,223)
    const int jg = g - i * GPR;
    const int j  = jg * 4;                   // first output col of this group
    const bool full = (j + 3 < NW);          // jg<=54: 4 patches; jg=55: 3

    const float* r0 = x + (size_t)b * NPB + (size_t)i * W + j;
    // 16B-aligned: NPB, W multiples of 4 and j%4==0
    float4 p00 = *(const float4*)(r0);               // row i,   ch0
    float4 p01 = *(const float4*)(r0 + PIXB);        // row i,   ch1
    float4 p10 = *(const float4*)(r0 + W);           // row i+1, ch0
    float4 p11 = *(const float4*)(r0 + W + PIXB);    // row i+1, ch1

    // per-pixel-pair trig: pcc = cos(a)*cos(bb), psa = sin(a)
    float pcc[2][5], psa[2][5];
    #define TRIG(pa, pb, PC, PS) do {                         \
        float _a  = ((pa) - gmin) * scale;                    \
        float _bb = ((pb) - gmin) * scale;                    \
        float _s, _c; __sincosf(_a, &_s, &_c);                \
        (PC) = _c * __cosf(_bb); (PS) = _s; } while (0)

    TRIG(p00.x, p01.x, pcc[0][0], psa[0][0]);
    TRIG(p00.y, p01.y, pcc[0][1], psa[0][1]);
    TRIG(p00.z, p01.z, pcc[0][2], psa[0][2]);
    TRIG(p00.w, p01.w, pcc[0][3], psa[0][3]);
    TRIG(p10.x, p11.x, pcc[1][0], psa[1][0]);
    TRIG(p10.y, p11.y, pcc[1][1], psa[1][1]);
    TRIG(p10.z, p11.z, pcc[1][2], psa[1][2]);
    TRIG(p10.w, p11.w, pcc[1][3], psa[1][3]);
    if (full) {
        float e0 = r0[4], e1 = (r0 + PIXB)[4];
        float e2 = (r0 + W)[4], e3 = (r0 + W + PIXB)[4];
        TRIG(e0, e1, pcc[0][4], psa[0][4]);
        TRIG(e2, e3, pcc[1][4], psa[1][4]);
    } else {
        pcc[0][4] = psa[0][4] = pcc[1][4] = psa[1][4] = 0.0f;
    }

    const int np = full ? 4 : 3;
    const size_t obase = ((size_t)(b * 4) * NH + i) * NW + j;
    #pragma unroll
    for (int dj = 0; dj < 4; ++dj) {
        if (dj >= np) break;
        float z0 = pcc[0][dj]     * cw0 - psa[0][dj]     * sw0;
        float z1 = pcc[0][dj + 1] * cw1 - psa[0][dj + 1] * sw1;
        float z2 = pcc[1][dj]     * cw2 - psa[1][dj]     * sw2;
        float z3 = pcc[1][dj + 1] * cw3 - psa[1][dj + 1] * sw3;
        float z01 = z0 * z1;
        out[obase + dj]             = z1 * z2 * z3;
        out[obase + dj + PER_B]     = z01;
        out[obase + dj + 2 * PER_B] = z01 * z2;
        out[obase + dj + 3 * PER_B] = z01 * z2 * z3;
    }
}

extern "C" void kernel_launch(void* const* d_in, const int* in_sizes, int n_in,
                              void* d_out, int out_size, void* d_ws, size_t ws_size,
                              hipStream_t stream) {
    const float* x   = (const float*)d_in[0];   // [8,2,224,224] f32
    const float* wts = (const float*)d_in[1];   // [1,4] f32
    float* out = (float*)d_out;                 // [8,4,223,223] f32
    float* ws  = (float*)d_ws;

    minmax_kernel<<<BATCH * BPB, 256, 0, stream>>>(x, wts, ws);
    quanv_kernel<<<dim3(BPB2, BATCH), 256, 0, stream>>>(x, ws, out);
}